// Round 10
// baseline (1788.285 us; speedup 1.0000x reference)
//
#include <hip/hip_runtime.h>
#include <cstdint>
#include <cstddef>

#define B_   32
#define T_   128
#define H_   1024
#define V_   32000
#define NBT  (B_*T_)   // 4096
#define G3H  (3*H_)    // 3072
#define NBLK 64
#define NTHR 768       // 12 waves: (gate 0..2) x (batch-half 0..1) x (k-half 0..1)
#define JB   16        // columns per block -> 48 W rows
#define BH_  (B_*H_)   // 32768 elements per h buffer

typedef short  short8  __attribute__((ext_vector_type(8)));
typedef float  f32x4   __attribute__((ext_vector_type(4)));

#define EMB_LDS (V_*4 + NBT*4)           // 144384

__device__ __forceinline__ unsigned short bf16_rtn(float f) {
    unsigned u = __float_as_uint(f);
    u += 0x7FFFu + ((u >> 16) & 1u);
    return (unsigned short)(u >> 16);
}

// ---------- prepass: gxT[r][bt] = Wih[r][tok[bt]] + bih[r] ----------
__global__ __launch_bounds__(1024) void gru_embed(
    const float* __restrict__ Wih,   // (3072,32000)
    const float* __restrict__ bih,   // (3072)
    const int*   __restrict__ xs,    // (B,T) flat = bt order
    float*       __restrict__ gxT)   // (3072, 4096)
{
    extern __shared__ char l[];
    float* rowL = (float*)l;              // 32000 floats
    int*   tokL = (int*)(l + V_ * 4);     // 4096 ints
    const int tid = threadIdx.x;
    const int r   = (int)blockIdx.x;

    for (int i = tid; i < NBT; i += 1024) tokL[i] = xs[i];
    const float4* src = (const float4*)(Wih + (size_t)r * V_);
    for (int i = tid; i < V_ / 4; i += 1024) ((float4*)rowL)[i] = src[i];
    __syncthreads();

    const float bias = bih[r];
    float* dst = gxT + (size_t)r * NBT;
    for (int i = tid; i < NBT; i += 1024) dst[i] = rowL[tokL[i]] + bias;
}

// ---------- transpose: gx2[bt][r] = gxT[r][bt] (LDS-tiled 32x32) ----------
__global__ __launch_bounds__(256) void gru_tr(
    const float* __restrict__ gxT,   // (3072, 4096)
    float*       __restrict__ gx2)   // (4096, 3072)
{
    __shared__ float tile[32][33];
    const int tx = threadIdx.x & 31;
    const int ty = threadIdx.x >> 5;
    const int c0 = (int)blockIdx.x * 32;   // bt tile
    const int r0 = (int)blockIdx.y * 32;   // row tile
    #pragma unroll
    for (int ii = 0; ii < 4; ++ii) {
        const int i = ty + ii * 8;
        tile[i][tx] = gxT[(size_t)(r0 + i) * NBT + c0 + tx];
    }
    __syncthreads();
    #pragma unroll
    for (int ii = 0; ii < 4; ++ii) {
        const int i = ty + ii * 8;
        gx2[(size_t)(c0 + i) * G3H + r0 + tx] = tile[tx][i];
    }
}

// ---------- persistent recurrent kernel ----------
// Per step: per-wave poll (k-half producers) -> direct global B-frags ->
// 48 chained MFMAs -> C-partials to LDS -> sync -> gates -> h sc1 store ->
// sync (drains h) -> flag publish -> outp stores (retire off-chain).
__global__ __launch_bounds__(NTHR) void gru_persist(
    const float* __restrict__ Whh,   // (3072,1024)
    const float* __restrict__ bhh,   // (3072)
    const float* __restrict__ gx2,   // (4096,3072) = gx[bt][row]
    unsigned*    __restrict__ hpk,   // T_ x (B,H) packed (hi16|lo16) h buffers
    int*         __restrict__ flags, // (NBLK*32) zeroed before launch
    float*       __restrict__ outp,  // (B,T,H)
    float*       __restrict__ hidout)// (B,H)
{
    __shared__ float ghp[2][48][33];   // k-half partial gh (50.7 KB)

    const int tid  = threadIdx.x;
    const int bid  = (int)blockIdx.x;
    const int j0   = bid * JB;
    const int lane = tid & 63;
    const int wid  = tid >> 6;         // 0..11
    const int g    = wid >> 2;         // gate 0..2
    const int bh   = (wid >> 1) & 1;   // batch half
    const int kh   = wid & 1;          // k half

    // ---- W A-fragments (split bf16 hi/lo), loop-invariant ----
    short8 wAhi[16], wAlo[16];
    {
        const int   arow = lane & 15;
        const int   q    = lane >> 4;
        const float* wr  = Whh + (size_t)(g * H_ + j0 + arow) * H_;
        #pragma unroll
        for (int kkl = 0; kkl < 16; ++kkl) {
            const int kk = kh * 16 + kkl;
            const float4 w0 = *(const float4*)(wr + kk * 32 + q * 8);
            const float4 w1 = *(const float4*)(wr + kk * 32 + q * 8 + 4);
            const float wv[8] = {w0.x, w0.y, w0.z, w0.w, w1.x, w1.y, w1.z, w1.w};
            short8 hi8, lo8;
            #pragma unroll
            for (int j = 0; j < 8; ++j) {
                const unsigned short h = bf16_rtn(wv[j]);
                const float hf = __uint_as_float((unsigned)h << 16);
                hi8[j] = (short)h;
                lo8[j] = (short)bf16_rtn(wv[j] - hf);
            }
            wAhi[kkl] = hi8;
            wAlo[kkl] = lo8;
        }
    }

    // ---- B-frag global addressing: lane reads h[brow][kk*32 + bq*8 .. +8] ----
    const int brow = bh * 16 + (lane & 15);
    const int bq   = lane >> 4;
    const int pb   = kh * 32 + (lane & 31);   // producer block this lane polls

    // ---- gate-thread constants (tid<512): jj = tid&15 col, b = tid>>4 ----
    const int jj = tid & 15;
    const int b  = tid >> 4;
    float bhh0 = 0.f, bhh1 = 0.f, bhh2 = 0.f;
    float nxg0 = 0.f, nxg1 = 0.f, nxg2 = 0.f;
    float hold = 0.f;
    if (tid < 512) {
        bhh0 = bhh[0 * H_ + j0 + jj];
        bhh1 = bhh[1 * H_ + j0 + jj];
        bhh2 = bhh[2 * H_ + j0 + jj];
        const float* gp = gx2 + (size_t)(b * T_) * G3H + j0 + jj;
        nxg0 = gp[0 * H_];
        nxg1 = gp[1 * H_];
        nxg2 = gp[2 * H_];
    }

    __syncthreads();

    #pragma unroll 1
    for (int t = 0; t < T_; ++t) {
        const unsigned* hp_prev = hpk + (size_t)(t - 1) * BH_;  // valid t>0
        unsigned*       hp_cur  = hpk + (size_t)t * BH_;

        // consume this step's gx; issue next step's (lands under the poll/MFMA)
        const float cg0 = nxg0, cg1 = nxg1, cg2 = nxg2;
        if (tid < 512 && t + 1 < T_) {
            const float* gp = gx2 + (size_t)(b * T_ + t + 1) * G3H + j0 + jj;
            nxg0 = gp[0 * H_];
            nxg1 = gp[1 * H_];
            nxg2 = gp[2 * H_];
        }

        f32x4 acc = {0.f, 0.f, 0.f, 0.f};
        if (t > 0) {
            // ---- per-wave poll: this wave's k-half needs producers kh*32..+32 ----
            {
                const int* fp = flags + pb * 32;
                int v;
                do {
                    v = __hip_atomic_load(fp, __ATOMIC_RELAXED,
                                          __HIP_MEMORY_SCOPE_AGENT);
                } while (!__all(v >= t));
            }
            asm volatile("" ::: "memory");   // B loads must stay below the poll

            // ---- direct global B-frags + chained split-bf16 MFMA ----
            const unsigned* hrow = hp_prev + (size_t)brow * H_ + bq * 8;
            #pragma unroll
            for (int kkl = 0; kkl < 16; ++kkl) {
                const int kk = kh * 16 + kkl;
                const uint4 p0 = *(const uint4*)(hrow + kk * 32);
                const uint4 p1 = *(const uint4*)(hrow + kk * 32 + 4);
                short8 bhi, blo;
                bhi[0] = (short)(p0.x >> 16); blo[0] = (short)(p0.x & 0xFFFFu);
                bhi[1] = (short)(p0.y >> 16); blo[1] = (short)(p0.y & 0xFFFFu);
                bhi[2] = (short)(p0.z >> 16); blo[2] = (short)(p0.z & 0xFFFFu);
                bhi[3] = (short)(p0.w >> 16); blo[3] = (short)(p0.w & 0xFFFFu);
                bhi[4] = (short)(p1.x >> 16); blo[4] = (short)(p1.x & 0xFFFFu);
                bhi[5] = (short)(p1.y >> 16); blo[5] = (short)(p1.y & 0xFFFFu);
                bhi[6] = (short)(p1.z >> 16); blo[6] = (short)(p1.z & 0xFFFFu);
                bhi[7] = (short)(p1.w >> 16); blo[7] = (short)(p1.w & 0xFFFFu);
                acc = __builtin_amdgcn_mfma_f32_16x16x32_bf16(wAhi[kkl], bhi, acc, 0, 0, 0);
                acc = __builtin_amdgcn_mfma_f32_16x16x32_bf16(wAhi[kkl], blo, acc, 0, 0, 0);
                acc = __builtin_amdgcn_mfma_f32_16x16x32_bf16(wAlo[kkl], bhi, acc, 0, 0, 0);
            }
        }

        // ---- C partials -> LDS (col=lane&15=batch, row=(lane>>4)*4+r) ----
        {
            const int bcol = bh * 16 + (lane & 15);
            #pragma unroll
            for (int r = 0; r < 4; ++r)
                ghp[kh][g * 16 + (lane >> 4) * 4 + r][bcol] = acc[r];
        }
        __syncthreads();

        // ---- gate math + h publish (threads 0..511) ----
        float hnew = 0.f;
        if (tid < 512) {
            float hr = bhh0, hz = bhh1, hn = bhh2;
            if (t > 0) {
                hr += ghp[0][0 * 16 + jj][b] + ghp[1][0 * 16 + jj][b];
                hz += ghp[0][1 * 16 + jj][b] + ghp[1][1 * 16 + jj][b];
                hn += ghp[0][2 * 16 + jj][b] + ghp[1][2 * 16 + jj][b];
            }
            const float rg = 1.f / (1.f + __expf(-(cg0 + hr)));
            const float zg = 1.f / (1.f + __expf(-(cg1 + hz)));
            const float tn = cg2 + rg * hn;
            const float e  = __expf(-2.f * fabsf(tn));
            const float m  = (1.f - e) / (1.f + e);
            const float ng = copysignf(m, tn);           // tanh, inf-safe
            hnew = (1.f - zg) * ng + zg * hold;
            hold = hnew;                                  // state stays in-register

            const unsigned short hh = bf16_rtn(hnew);
            const float hf = __uint_as_float((unsigned)hh << 16);
            const unsigned short hl = bf16_rtn(hnew - hf);
            const unsigned pk = ((unsigned)hh << 16) | (unsigned)hl;
            // device-coherent write-through (sc1); relaxed -> no wbl2/inv
            __hip_atomic_store(hp_cur + (size_t)b * H_ + j0 + jj, pk,
                               __ATOMIC_RELAXED, __HIP_MEMORY_SCOPE_AGENT);
        }

        // ---- drain h stores (vmcnt(0) inside syncthreads), then publish ----
        __syncthreads();
        if (tid == 0) {
            __hip_atomic_store(&flags[bid * 32], t + 1,
                               __ATOMIC_RELAXED, __HIP_MEMORY_SCOPE_AGENT);
        }

        // ---- output stores AFTER publish: retire under the next step ----
        if (tid < 512) {
            outp[((size_t)b * T_ + t) * H_ + j0 + jj] = hnew;
            if (t == T_ - 1) hidout[(size_t)b * H_ + j0 + jj] = hnew;
        }
    }
}

extern "C" void kernel_launch(void* const* d_in, const int* in_sizes, int n_in,
                              void* d_out, int out_size, void* d_ws, size_t ws_size,
                              hipStream_t stream) {
    const int*   xs  = (const int*)  d_in[0];
    const float* Wih = (const float*)d_in[1];
    const float* Whh = (const float*)d_in[2];
    const float* bih = (const float*)d_in[3];
    const float* bhh = (const float*)d_in[4];

    float* outp = (float*)d_out;
    float* hid  = outp + (size_t)B_ * T_ * H_;

    unsigned* hpk   = (unsigned*)d_ws;                       // 16 MB
    int*      flags = (int*)(hpk + (size_t)T_ * BH_);        // 8 KB
    float*    gxT   = (float*)(flags + NBLK * 32);           // 50 MB
    float*    gx2   = gxT + (size_t)G3H * NBT;               // 50 MB

    (void)hipMemsetAsync(flags, 0, (size_t)NBLK * 32 * sizeof(int), stream);

    (void)hipFuncSetAttribute((const void*)gru_embed,
                              hipFuncAttributeMaxDynamicSharedMemorySize,
                              (int)EMB_LDS);

    gru_embed<<<G3H, 1024, EMB_LDS, stream>>>(Wih, bih, xs, gxT);
    gru_tr<<<dim3(NBT / 32, G3H / 32), 256, 0, stream>>>(gxT, gx2);
    gru_persist<<<NBLK, NTHR, 0, stream>>>(
        Whh, bhh, gx2, hpk, flags, outp, hid);

    (void)in_sizes; (void)n_in; (void)out_size; (void)ws_size;
}

// Round 11
// 1760.234 us; speedup vs baseline: 1.0159x; 1.0159x over previous
//
#include <hip/hip_runtime.h>
#include <cstdint>
#include <cstddef>

#define B_   32
#define T_   128
#define H_   1024
#define V_   32000
#define NBT  (B_*T_)   // 4096
#define G3H  (3*H_)    // 3072
#define BH_  (B_*H_)   // 32768

typedef short short8 __attribute__((ext_vector_type(8)));
typedef short short4v __attribute__((ext_vector_type(4)));
typedef float f32x4  __attribute__((ext_vector_type(4)));

#define EMB_LDS (V_*4 + NBT*4)   // 144384

__device__ __forceinline__ unsigned short bf16_rtn(float f) {
    unsigned u = __float_as_uint(f);
    u += 0x7FFFu + ((u >> 16) & 1u);
    return (unsigned short)(u >> 16);
}

// ---------- prepass 1: gxT[r][bt] = Wih[r][tok[bt]] + bih[r] ----------
__global__ __launch_bounds__(1024) void gru_embed(
    const float* __restrict__ Wih, const float* __restrict__ bih,
    const int* __restrict__ xs, float* __restrict__ gxT)
{
    extern __shared__ char l[];
    float* rowL = (float*)l;
    int*   tokL = (int*)(l + V_ * 4);
    const int tid = threadIdx.x;
    const int r   = (int)blockIdx.x;

    for (int i = tid; i < NBT; i += 1024) tokL[i] = xs[i];
    const float4* src = (const float4*)(Wih + (size_t)r * V_);
    for (int i = tid; i < V_ / 4; i += 1024) ((float4*)rowL)[i] = src[i];
    __syncthreads();

    const float bias = bih[r];
    float* dst = gxT + (size_t)r * NBT;
    for (int i = tid; i < NBT; i += 1024) dst[i] = rowL[tokL[i]] + bias;
}

// ---------- prepass 2: gx2[bt][r] = gxT[r][bt] ----------
__global__ __launch_bounds__(256) void gru_tr(
    const float* __restrict__ gxT, float* __restrict__ gx2)
{
    __shared__ float tile[32][33];
    const int tx = threadIdx.x & 31;
    const int ty = threadIdx.x >> 5;
    const int c0 = (int)blockIdx.x * 32;
    const int r0 = (int)blockIdx.y * 32;
    #pragma unroll
    for (int ii = 0; ii < 4; ++ii) {
        const int i = ty + ii * 8;
        tile[i][tx] = gxT[(size_t)(r0 + i) * NBT + c0 + tx];
    }
    __syncthreads();
    #pragma unroll
    for (int ii = 0; ii < 4; ++ii) {
        const int i = ty + ii * 8;
        gx2[(size_t)(c0 + i) * G3H + r0 + tx] = tile[tx][i];
    }
}

// ---------- prepass 3: split Whh -> bf16 hi/lo arrays (row-major) ----------
__global__ __launch_bounds__(256) void gru_wcvt(
    const float* __restrict__ Whh,
    unsigned short* __restrict__ Whi, unsigned short* __restrict__ Wlo)
{
    const int r  = (int)blockIdx.x;           // 0..3071
    const int c4 = (int)threadIdx.x * 4;      // 0..1020
    const float4 w = *(const float4*)(Whh + (size_t)r * H_ + c4);
    const float wv[4] = {w.x, w.y, w.z, w.w};
    short4v hi4, lo4;
    #pragma unroll
    for (int j = 0; j < 4; ++j) {
        const unsigned short h = bf16_rtn(wv[j]);
        const float hf = __uint_as_float((unsigned)h << 16);
        hi4[j] = (short)h;
        lo4[j] = (short)bf16_rtn(wv[j] - hf);
    }
    *(short4v*)(Whi + (size_t)r * H_ + c4) = hi4;
    *(short4v*)(Wlo + (size_t)r * H_ + c4) = lo4;
}

// ---------- per-step kernel: one dispatch per t, CP is the barrier ----------
// 128 blocks = (jg 0..63 col-group of 16) x (bh batch-half). 384 thr = 6 waves
// = (gate g 0..2) x (k-half kh). Per wave: 16 k-steps x 3 split-bf16 MFMAs
// (chained acc). No atomics, no fences: kernel boundary = coherence.
__global__ __launch_bounds__(384) void gru_step(
    const unsigned short* __restrict__ Whi,  // (3072,1024) bf16 hi
    const unsigned short* __restrict__ Wlo,  // (3072,1024) bf16 lo
    const float* __restrict__ bhh,           // (3072)
    const float* __restrict__ gx2,           // (4096,3072)
    unsigned short* __restrict__ hhiB,       // T x (B,H) bf16 hi of h
    unsigned short* __restrict__ hloB,       // T x (B,H) bf16 lo of h
    float*          __restrict__ hfB,        // T x (B,H) exact fp32 h
    float* __restrict__ outp,                // (B,T,H)
    float* __restrict__ hidout,              // (B,H)
    int t)
{
    __shared__ float ghp[2][48][17];   // k-half partials, 6.5 KB

    const int tid  = threadIdx.x;
    const int bidx = (int)blockIdx.x;
    const int jg   = bidx >> 1;
    const int bh   = bidx & 1;
    const int j0   = jg * 16;
    const int lane = tid & 63;
    const int wid  = tid >> 6;        // 0..5
    const int g    = wid >> 1;        // gate
    const int kh   = wid & 1;         // k half
    const int arow = lane & 15;
    const int q    = lane >> 4;

    // ---- gate-thread early loads (issue before MFMA phase) ----
    const int jj  = tid & 15;
    const int b16 = (tid >> 4) & 15;
    const int b   = bh * 16 + b16;
    float xg0 = 0.f, xg1 = 0.f, xg2 = 0.f, hold = 0.f;
    float bb0 = 0.f, bb1 = 0.f, bb2 = 0.f;
    if (tid < 256) {
        const float* gp = gx2 + (size_t)(b * T_ + t) * G3H + j0 + jj;
        xg0 = gp[0];
        xg1 = gp[H_];
        xg2 = gp[2 * H_];
        bb0 = bhh[j0 + jj];
        bb1 = bhh[H_ + j0 + jj];
        bb2 = bhh[2 * H_ + j0 + jj];
        if (t > 0) hold = hfB[(size_t)(t - 1) * BH_ + (size_t)b * H_ + j0 + jj];
    }

    // ---- MFMA: A = W rows (g*H+j0+arow), B = h rows (bh*16+arow) ----
    f32x4 acc = {0.f, 0.f, 0.f, 0.f};
    if (t > 0) {
        const unsigned short* hh = hhiB + (size_t)(t - 1) * BH_ + (size_t)(bh * 16 + arow) * H_;
        const unsigned short* hl = hloB + (size_t)(t - 1) * BH_ + (size_t)(bh * 16 + arow) * H_;
        const unsigned short* wh = Whi + (size_t)(g * H_ + j0 + arow) * H_;
        const unsigned short* wl = Wlo + (size_t)(g * H_ + j0 + arow) * H_;
        #pragma unroll
        for (int kkl = 0; kkl < 16; ++kkl) {
            const int ko = (kh * 16 + kkl) * 32 + q * 8;
            const short8 ahi = *(const short8*)(wh + ko);
            const short8 alo = *(const short8*)(wl + ko);
            const short8 bhi = *(const short8*)(hh + ko);
            const short8 blo = *(const short8*)(hl + ko);
            acc = __builtin_amdgcn_mfma_f32_16x16x32_bf16(ahi, bhi, acc, 0, 0, 0);
            acc = __builtin_amdgcn_mfma_f32_16x16x32_bf16(ahi, blo, acc, 0, 0, 0);
            acc = __builtin_amdgcn_mfma_f32_16x16x32_bf16(alo, bhi, acc, 0, 0, 0);
        }
    }

    // ---- C partials -> LDS (col = lane&15 = batch, row = q*4+r = hidden) ----
    #pragma unroll
    for (int r = 0; r < 4; ++r)
        ghp[kh][g * 16 + q * 4 + r][lane & 15] = acc[r];
    __syncthreads();

    // ---- gate math + h/out stores (threads 0..255) ----
    if (tid < 256) {
        const float hr = bb0 + ghp[0][jj][b16]      + ghp[1][jj][b16];
        const float hz = bb1 + ghp[0][16 + jj][b16] + ghp[1][16 + jj][b16];
        const float hn = bb2 + ghp[0][32 + jj][b16] + ghp[1][32 + jj][b16];
        const float rg = 1.f / (1.f + __expf(-(xg0 + hr)));
        const float zg = 1.f / (1.f + __expf(-(xg1 + hz)));
        const float tn = xg2 + rg * hn;
        const float e  = __expf(-2.f * fabsf(tn));
        const float m  = (1.f - e) / (1.f + e);
        const float ng = copysignf(m, tn);           // tanh, inf-safe
        const float hnew = (1.f - zg) * ng + zg * hold;

        const unsigned short hhw = bf16_rtn(hnew);
        const float hf = __uint_as_float((unsigned)hhw << 16);
        const unsigned short hlw = bf16_rtn(hnew - hf);
        const size_t ci = (size_t)t * BH_ + (size_t)b * H_ + j0 + jj;
        hhiB[ci] = hhw;
        hloB[ci] = hlw;
        hfB[ci]  = hnew;
        outp[((size_t)b * T_ + t) * H_ + j0 + jj] = hnew;
        if (t == T_ - 1) hidout[(size_t)b * H_ + j0 + jj] = hnew;
    }
}

extern "C" void kernel_launch(void* const* d_in, const int* in_sizes, int n_in,
                              void* d_out, int out_size, void* d_ws, size_t ws_size,
                              hipStream_t stream) {
    const int*   xs  = (const int*)  d_in[0];
    const float* Wih = (const float*)d_in[1];
    const float* Whh = (const float*)d_in[2];
    const float* bih = (const float*)d_in[3];
    const float* bhh = (const float*)d_in[4];

    float* outp = (float*)d_out;
    float* hid  = outp + (size_t)B_ * T_ * H_;

    // ws layout (all sizes 2MB-multiples -> aligned)
    char* w = (char*)d_ws;
    float*          gxT  = (float*)w;          w += (size_t)G3H * NBT * 4;   // 50 MB
    float*          gx2  = (float*)w;          w += (size_t)G3H * NBT * 4;   // 50 MB
    unsigned short* Whi  = (unsigned short*)w; w += (size_t)G3H * H_ * 2;    // 6.3 MB
    unsigned short* Wlo  = (unsigned short*)w; w += (size_t)G3H * H_ * 2;    // 6.3 MB
    unsigned short* hhiB = (unsigned short*)w; w += (size_t)T_ * BH_ * 2;    // 8 MB
    unsigned short* hloB = (unsigned short*)w; w += (size_t)T_ * BH_ * 2;    // 8 MB
    float*          hfB  = (float*)w;                                        // 16 MB

    (void)hipFuncSetAttribute((const void*)gru_embed,
                              hipFuncAttributeMaxDynamicSharedMemorySize,
                              (int)EMB_LDS);

    gru_wcvt<<<G3H, 256, 0, stream>>>(Whh, Whi, Wlo);
    gru_embed<<<G3H, 1024, EMB_LDS, stream>>>(Wih, bih, xs, gxT);
    gru_tr<<<dim3(NBT / 32, G3H / 32), 256, 0, stream>>>(gxT, gx2);

    for (int t = 0; t < T_; ++t) {
        gru_step<<<128, 384, 0, stream>>>(
            Whi, Wlo, bhh, gx2, hhiB, hloB, hfB, outp, hid, t);
    }

    (void)in_sizes; (void)n_in; (void)out_size; (void)ws_size;
}

// Round 13
// 813.103 us; speedup vs baseline: 2.1993x; 2.1648x over previous
//
#include <hip/hip_runtime.h>
#include <cstdint>
#include <cstddef>

#define B_   32
#define T_   128
#define H_   1024
#define V_   32000
#define NBT  (B_*T_)   // 4096
#define G3H  (3*H_)    // 3072
#define BH_  (B_*H_)   // 32768
#define NBLK 256
#define NTHR 512
#define JB   4         // columns per block; 12 W rows packed as MFMA rows g*4+jj

typedef short short8 __attribute__((ext_vector_type(8)));
typedef float f32x4  __attribute__((ext_vector_type(4)));

#define EMB_LDS (V_*4 + NBT*4)   // 144384

__device__ __forceinline__ unsigned short bf16_rtn(float f) {
    unsigned u = __float_as_uint(f);
    u += 0x7FFFu + ((u >> 16) & 1u);
    return (unsigned short)(u >> 16);
}

// ---------- prepass 1: gxT[r][bt] = Wih[r][tok[bt]] + bih[r] ----------
__global__ __launch_bounds__(1024) void gru_embed(
    const float* __restrict__ Wih, const float* __restrict__ bih,
    const int* __restrict__ xs, float* __restrict__ gxT)
{
    extern __shared__ char l[];
    float* rowL = (float*)l;
    int*   tokL = (int*)(l + V_ * 4);
    const int tid = threadIdx.x;
    const int r   = (int)blockIdx.x;

    for (int i = tid; i < NBT; i += 1024) tokL[i] = xs[i];
    const float4* src = (const float4*)(Wih + (size_t)r * V_);
    for (int i = tid; i < V_ / 4; i += 1024) ((float4*)rowL)[i] = src[i];
    __syncthreads();

    const float bias = bih[r];
    float* dst = gxT + (size_t)r * NBT;
    for (int i = tid; i < NBT; i += 1024) dst[i] = rowL[tokL[i]] + bias;
}

// ---------- prepass 2: gx2[bt][r] = gxT[r][bt] ----------
__global__ __launch_bounds__(256) void gru_tr(
    const float* __restrict__ gxT, float* __restrict__ gx2)
{
    __shared__ float tile[32][33];
    const int tx = threadIdx.x & 31;
    const int ty = threadIdx.x >> 5;
    const int c0 = (int)blockIdx.x * 32;
    const int r0 = (int)blockIdx.y * 32;
    #pragma unroll
    for (int ii = 0; ii < 4; ++ii) {
        const int i = ty + ii * 8;
        tile[i][tx] = gxT[(size_t)(r0 + i) * NBT + c0 + tx];
    }
    __syncthreads();
    #pragma unroll
    for (int ii = 0; ii < 4; ++ii) {
        const int i = ty + ii * 8;
        gx2[(size_t)(c0 + i) * G3H + r0 + tx] = tile[tx][i];
    }
}

// ---------- persistent recurrent kernel ----------
// r5-verified sync skeleton (256 monotone flags, 256 sc1 pollers, publish
// after drain) + r8-verified split-bf16 MFMA + r10-verified direct-global
// packed-h B-frags + gx prepass inputs. 8 waves = (bh batch-half, kq4
// k-quarter). MFMA tile rows = g*4+jj pack all 3 gates x 4 cols.
__global__ __launch_bounds__(NTHR) void gru_persist(
    const float* __restrict__ Whh,   // (3072,1024)
    const float* __restrict__ bhh,   // (3072)
    const float* __restrict__ gx2,   // (4096,3072)
    unsigned*    __restrict__ hpk,   // T x (B,H) packed (bf16hi|bf16lo) h
    int*         __restrict__ flags, // 256*32 ints, zeroed per launch
    float*       __restrict__ outp,  // (B,T,H)
    float*       __restrict__ hidout)// (B,H)
{
    __shared__ float ghp[4][2][16][17];   // k-quarter partials, 8.7 KB

    const int tid  = threadIdx.x;
    const int bid  = (int)blockIdx.x;
    const int j0   = bid * JB;
    const int lane = tid & 63;
    const int wid  = tid >> 6;     // 0..7
    const int bh   = wid & 1;      // batch half
    const int kq4  = wid >> 1;     // k quarter
    const int arow = lane & 15;    // A row / B col
    const int q    = lane >> 4;

    // ---- W A-fragments (split bf16 hi/lo) -> VGPRs once.
    //      MFMA row r = g*4+jj -> W row (r>>2)*H + j0 + (r&3); rows 12..15 pad.
    short8 wAhi[8], wAlo[8];
    {
        const int r12 = arow < 12 ? arow : 11;   // clamp: pad rows, C discarded
        const float* wr = Whh + (size_t)((r12 >> 2) * H_ + j0 + (r12 & 3)) * H_;
        #pragma unroll
        for (int kkl = 0; kkl < 8; ++kkl) {
            const int ko = (kq4 * 8 + kkl) * 32 + q * 8;
            const float4 w0 = *(const float4*)(wr + ko);
            const float4 w1 = *(const float4*)(wr + ko + 4);
            const float wv[8] = {w0.x,w0.y,w0.z,w0.w,w1.x,w1.y,w1.z,w1.w};
            short8 hi8, lo8;
            #pragma unroll
            for (int j = 0; j < 8; ++j) {
                const unsigned short h = bf16_rtn(wv[j]);
                const float hf = __uint_as_float((unsigned)h << 16);
                hi8[j] = (short)h;
                lo8[j] = (short)bf16_rtn(wv[j] - hf);
            }
            wAhi[kkl] = hi8;
            wAlo[kkl] = lo8;
        }
    }

    // ---- gate-thread constants (tid<128): jj = tid&3 col, gb = tid>>2 batch ----
    const int jj  = tid & 3;
    const int gb  = tid >> 2;
    const int b16 = gb & 15;
    const int bh2 = gb >> 4;
    float bb0 = 0.f, bb1 = 0.f, bb2 = 0.f, hold = 0.f;
    if (tid < 128) {
        bb0 = bhh[j0 + jj];
        bb1 = bhh[H_ + j0 + jj];
        bb2 = bhh[2 * H_ + j0 + jj];
    }

    #pragma unroll 1
    for (int t = 0; t < T_; ++t) {
        // gx loads for THIS step (independent of h; overlap the poll)
        float xg0 = 0.f, xg1 = 0.f, xg2 = 0.f;
        if (tid < 128) {
            const float* gp = gx2 + (size_t)(gb * T_ + t) * G3H + j0 + jj;
            xg0 = gp[0];
            xg1 = gp[H_];
            xg2 = gp[2 * H_];
        }

        // ---- r5 rendezvous: 256 pollers, one sc1 flag each ----
        if (t > 0 && tid < NBLK) {
            int v;
            do {
                v = __hip_atomic_load(&flags[tid * 32], __ATOMIC_RELAXED,
                                      __HIP_MEMORY_SCOPE_AGENT);
            } while (v < t);
        }
        __syncthreads();

        // ---- split-bf16 MFMA GEMM, B-frags direct from global packed h ----
        f32x4 ahh = {0.f,0.f,0.f,0.f};
        f32x4 ahl = {0.f,0.f,0.f,0.f};
        f32x4 alh = {0.f,0.f,0.f,0.f};
        if (t > 0) {
            const unsigned* hb = hpk + (size_t)(t - 1) * BH_
                               + (size_t)(bh * 16 + arow) * H_ + q * 8;
            #pragma unroll
            for (int kkl = 0; kkl < 8; ++kkl) {
                const int ko = (kq4 * 8 + kkl) * 32;
                const uint4 p0 = *(const uint4*)(hb + ko);
                const uint4 p1 = *(const uint4*)(hb + ko + 4);
                short8 bhi, blo;
                bhi[0] = (short)(p0.x >> 16); blo[0] = (short)(p0.x & 0xFFFFu);
                bhi[1] = (short)(p0.y >> 16); blo[1] = (short)(p0.y & 0xFFFFu);
                bhi[2] = (short)(p0.z >> 16); blo[2] = (short)(p0.z & 0xFFFFu);
                bhi[3] = (short)(p0.w >> 16); blo[3] = (short)(p0.w & 0xFFFFu);
                bhi[4] = (short)(p1.x >> 16); blo[4] = (short)(p1.x & 0xFFFFu);
                bhi[5] = (short)(p1.y >> 16); blo[5] = (short)(p1.y & 0xFFFFu);
                bhi[6] = (short)(p1.z >> 16); blo[6] = (short)(p1.z & 0xFFFFu);
                bhi[7] = (short)(p1.w >> 16); blo[7] = (short)(p1.w & 0xFFFFu);
                ahh = __builtin_amdgcn_mfma_f32_16x16x32_bf16(wAhi[kkl], bhi, ahh, 0, 0, 0);
                ahl = __builtin_amdgcn_mfma_f32_16x16x32_bf16(wAhi[kkl], blo, ahl, 0, 0, 0);
                alh = __builtin_amdgcn_mfma_f32_16x16x32_bf16(wAlo[kkl], bhi, alh, 0, 0, 0);
            }
        }

        // ---- C partials -> LDS (row m=q*4+r, col=arow=batch) ----
        #pragma unroll
        for (int r = 0; r < 4; ++r)
            ghp[kq4][bh][q * 4 + r][arow] = ahh[r] + ahl[r] + alh[r];
        __syncthreads();

        // ---- gates + packed-h publish (threads 0..127) ----
        float hnew = 0.f;
        if (tid < 128) {
            float s0 = 0.f, s1 = 0.f, s2 = 0.f;
            #pragma unroll
            for (int k4 = 0; k4 < 4; ++k4) {
                s0 += ghp[k4][bh2][0 * 4 + jj][b16];
                s1 += ghp[k4][bh2][1 * 4 + jj][b16];
                s2 += ghp[k4][bh2][2 * 4 + jj][b16];
            }
            const float rg = 1.f / (1.f + __expf(-(xg0 + bb0 + s0)));
            const float zg = 1.f / (1.f + __expf(-(xg1 + bb1 + s1)));
            const float tn = xg2 + bb2 + s2 + (rg - 1.f) * (bb2 + s2); // = xg2 + rg*(bb2+s2)? no — keep explicit:
            const float tnn = xg2 + rg * (bb2 + s2);
            const float e  = __expf(-2.f * fabsf(tnn));
            const float m  = (1.f - e) / (1.f + e);
            const float ng = copysignf(m, tnn);          // tanh, inf-safe
            hnew = (1.f - zg) * ng + zg * hold;
            hold = hnew;
            (void)tn;

            const unsigned short hh = bf16_rtn(hnew);
            const float hf = __uint_as_float((unsigned)hh << 16);
            const unsigned short hl = bf16_rtn(hnew - hf);
            const unsigned pk = ((unsigned)hh << 16) | (unsigned)hl;
            // device-coherent write-through (sc1); relaxed -> no wbl2/inv
            __hip_atomic_store(hpk + (size_t)t * BH_ + (size_t)gb * H_ + j0 + jj,
                               pk, __ATOMIC_RELAXED, __HIP_MEMORY_SCOPE_AGENT);
        }

        // ---- drain h stores (vmcnt0 in syncthreads) then publish flag ----
        __syncthreads();
        if (tid == 0) {
            __hip_atomic_store(&flags[bid * 32], t + 1,
                               __ATOMIC_RELAXED, __HIP_MEMORY_SCOPE_AGENT);
        }

        // ---- HBM output stores AFTER publish (off the critical chain) ----
        if (tid < 128) {
            outp[((size_t)gb * T_ + t) * H_ + j0 + jj] = hnew;
            if (t == T_ - 1) hidout[(size_t)gb * H_ + j0 + jj] = hnew;
        }
    }
}

extern "C" void kernel_launch(void* const* d_in, const int* in_sizes, int n_in,
                              void* d_out, int out_size, void* d_ws, size_t ws_size,
                              hipStream_t stream) {
    const int*   xs  = (const int*)  d_in[0];
    const float* Wih = (const float*)d_in[1];
    const float* Whh = (const float*)d_in[2];
    const float* bih = (const float*)d_in[3];
    const float* bhh = (const float*)d_in[4];

    float* outp = (float*)d_out;
    float* hid  = outp + (size_t)B_ * T_ * H_;

    char* p = (char*)d_ws;
    unsigned* hpk   = (unsigned*)p;  p += (size_t)T_ * BH_ * 4;    // 16 MB
    float*    gxT   = (float*)p;     p += (size_t)G3H * NBT * 4;   // 50 MB
    float*    gx2   = (float*)p;     p += (size_t)G3H * NBT * 4;   // 50 MB
    int*      flags = (int*)p;                                     // 32 KB

    // zero flags every launch (graph-replay deterministic)
    (void)hipMemsetAsync(flags, 0, (size_t)NBLK * 32 * sizeof(int), stream);

    (void)hipFuncSetAttribute((const void*)gru_embed,
                              hipFuncAttributeMaxDynamicSharedMemorySize,
                              (int)EMB_LDS);

    gru_embed<<<G3H, 1024, EMB_LDS, stream>>>(Wih, bih, xs, gxT);
    gru_tr<<<dim3(NBT / 32, G3H / 32), 256, 0, stream>>>(gxT, gx2);
    gru_persist<<<NBLK, NTHR, 0, stream>>>(
        Whh, bhh, gx2, hpk, flags, outp, hid);

    (void)in_sizes; (void)n_in; (void)out_size; (void)ws_size;
}